// Round 9
// baseline (1810.798 us; speedup 1.0000x reference)
//
#include <hip/hip_runtime.h>
#include <math.h>

// LatentFNO: B=32, T=24, R=512, W=128, M=64 modes, 4 layers, 12 steps.
// Round 9: spectral dispatch latency attack (arithmetic unchanged, bitwise
// identical): (a) dft re-tiled 32x32 -> 512 blocks (2/CU overlap), BK=64
// (16 barriers vs 32); (b) modemix stages ALL of K=128 in 69.6 KB LDS ->
// ONE barrier (was 8). idft/head unchanged from round 8.
// Math: exact 3-term bf16 split (A1B1+A1B2+A2B1).

#define NB 32
#define NR 512
#define NW 128
#define NM 64
#define NTH 24
#define NLAY 4
#define NSTEPS 12
#define SEQROWS 36

typedef unsigned short u16;
typedef unsigned int u32;
typedef __attribute__((ext_vector_type(8))) short bf16x8;
typedef __attribute__((ext_vector_type(4))) float f32x4;
#define MFMA16(a, b, c) __builtin_amdgcn_mfma_f32_16x16x32_bf16((a), (b), (c), 0, 0, 0)

__device__ __forceinline__ float gelu_exact(float x) {
    return 0.5f * x * (1.0f + erff(x * 0.70710678118654752f));
}
__device__ __forceinline__ float bf2f(u16 u) {
    union { u32 i; float f; } v; v.i = ((u32)u) << 16; return v.f;
}
__device__ __forceinline__ u16 f2bf_hi(float x) {
    union { float f; u32 i; } v; v.f = x; return (u16)(v.i >> 16);
}
__device__ __forceinline__ u16 f2bf_lo(float x) {
    float h = bf2f(f2bf_hi(x));
    return f2bf_hi(x - h);
}
__device__ __forceinline__ bf16x8 negbf(bf16x8 a) {
#pragma unroll
    for (int i = 0; i < 8; i++) a[i] ^= (short)0x8000;
    return a;
}

// ---------------------------------------------------------------------------
// Tables: F planes [mc=128][r=512]; GT planes [r=512][mc=128].
// ---------------------------------------------------------------------------
__global__ void build_tables_planes(u16* __restrict__ f1, u16* __restrict__ f2,
                                    u16* __restrict__ gt1, u16* __restrict__ gt2) {
    int idx = blockIdx.x * 256 + threadIdx.x;   // 65536: mc*512 + r
    int mc = idx >> 9, r = idx & 511, m = mc & 63;
    int p = (m * r) & 511;
    float a = (float)p * (1.0f / 256.0f);
    float c = cospif(a), s = sinpif(a);
    float Fv = (mc < 64) ? c : -s;
    float cm = (m == 0) ? (1.0f / 512.0f) : (2.0f / 512.0f);
    float Gv = (mc < 64) ? cm * c : ((m == 0) ? 0.0f : -cm * s);
    f1[idx] = f2bf_hi(Fv); f2[idx] = f2bf_lo(Fv);
    size_t g = (size_t)r * 128 + mc;
    gt1[g] = f2bf_hi(Gv); gt2[g] = f2bf_lo(Gv);
}

// spec_w (l,i,o,m) -> planes [l][m][o][i] hi/lo, coalesced both directions.
__global__ __launch_bounds__(256) void prep_specw(const float* __restrict__ wr, const float* __restrict__ wi,
                           u16* __restrict__ wr1, u16* __restrict__ wr2,
                           u16* __restrict__ wi1, u16* __restrict__ wi2) {
    __shared__ float tile[128][65];
    int l = blockIdx.x >> 7, o = blockIdx.x & 127;
    int tid = threadIdx.x;
    size_t sbase = (size_t)l * 1048576 + (size_t)o * 64;
    size_t dbase = (size_t)l * 64 * 16384 + (size_t)o * 128;
    for (int pass = 0; pass < 2; pass++) {
        const float* src = pass ? wi : wr;
        u16* d1 = pass ? wi1 : wr1;
        u16* d2 = pass ? wi2 : wr2;
        if (pass) __syncthreads();
        for (int e = tid; e < 8192; e += 256) {
            int i = e >> 6, m = e & 63;
            tile[i][m] = src[sbase + (size_t)i * 8192 + m];
        }
        __syncthreads();
        for (int e = tid; e < 4096; e += 256) {
            int m = e >> 6, i2 = (e & 63) * 2;
            float v0 = tile[i2][m], v1 = tile[i2 + 1][m];
            u32 hh = (u32)f2bf_hi(v0) | ((u32)f2bf_hi(v1) << 16);
            u32 ll = (u32)f2bf_lo(v0) | ((u32)f2bf_lo(v1) << 16);
            size_t d = dbase + (size_t)m * 16384 + i2;
            *(u32*)&d1[d] = hh;
            *(u32*)&d2[d] = ll;
        }
    }
}

__global__ void prep_cw(const float* __restrict__ cw, u16* __restrict__ c1, u16* __restrict__ c2) {
    int idx = blockIdx.x * 256 + threadIdx.x;   // 65536
    float v = cw[idx];
    c1[idx] = f2bf_hi(v); c2[idx] = f2bf_lo(v);
}

// fc1_w [c=128][j=256] -> fc1t planes [j][c] hi/lo
__global__ void prep_fc1t(const float* __restrict__ fc1_w,
                          u16* __restrict__ f11, u16* __restrict__ f12) {
    int idx = blockIdx.x * 256 + threadIdx.x;   // 32768: j*128 + c
    int j = idx >> 7, c = idx & 127;
    float v = fc1_w[(size_t)c * 256 + j];
    f11[idx] = f2bf_hi(v); f12[idx] = f2bf_lo(v);
}

__global__ void init_seq_kernel(const float* __restrict__ z, float* __restrict__ seq) {
    int idx = blockIdx.x * 256 + threadIdx.x;    // < 32*24*512
    int b = idx / (NTH * NR);
    int rem = idx - b * (NTH * NR);
    seq[(size_t)b * SEQROWS * NR + rem] = z[idx];
}

// ---------------------------------------------------------------------------
// fc0 (fp32), step 0 only: writes ht[b][r][c] AND htc[b][c][r] planes.
// ---------------------------------------------------------------------------
__global__ __launch_bounds__(256) void fc0_kernel(const float* __restrict__ seq,
        const float* __restrict__ t_grid, const float* __restrict__ fc0_w,
        const float* __restrict__ fc0_b, u16* __restrict__ ht1, u16* __restrict__ ht2,
        u16* __restrict__ htc1, u16* __restrict__ htc2, int step) {
    __shared__ float wlds[28 * 128];
    __shared__ float blds[128];
    int b = blockIdx.y, rblk = blockIdx.x;
    int tid = threadIdx.x;
    for (int t = tid; t < 28 * 128; t += 256) wlds[t] = fc0_w[t];
    if (tid < 128) blds[tid] = fc0_b[tid];
    __syncthreads();
    int lane = tid & 63, wq = tid >> 6;
    int r = rblk * 64 + lane;
    float sv[24];
    const float* sp = seq + ((size_t)b * SEQROWS + step) * NR + r;
#pragma unroll
    for (int t = 0; t < 24; t++) sv[t] = sp[(size_t)t * NR];
    float tt = t_grid[b * 24 + 23] + (float)(step + 1);
    float ang24 = 6.28318530717958647692f * tt * (1.0f / 24.0f);
    float ang168 = 6.28318530717958647692f * tt * (1.0f / 168.0f);
    float s24 = sinf(ang24), c24 = cosf(ang24), s168 = sinf(ang168);
    float xc = (float)r * (1.0f / 511.0f);
    size_t rowoff = ((size_t)b * NR + r) * NW;
#pragma unroll 2
    for (int w0 = 0; w0 < 32; w0 += 2) {
        float acc2[2];
#pragma unroll
        for (int q = 0; q < 2; q++) {
            int w = wq * 32 + w0 + q;
            float acc = blds[w];
#pragma unroll
            for (int t = 0; t < 24; t++) acc += sv[t] * wlds[t * 128 + w];
            acc += s24 * wlds[24 * 128 + w] + c24 * wlds[25 * 128 + w]
                 + s168 * wlds[26 * 128 + w] + xc * wlds[27 * 128 + w];
            acc2[q] = acc;
        }
        u16 h0 = f2bf_hi(acc2[0]), h1 = f2bf_hi(acc2[1]);
        u16 l0 = f2bf_lo(acc2[0]), l1 = f2bf_lo(acc2[1]);
        size_t off = rowoff + wq * 32 + w0;
        *(u32*)&ht1[off] = (u32)h0 | ((u32)h1 << 16);
        *(u32*)&ht2[off] = (u32)l0 | ((u32)l1 << 16);
        int w = wq * 32 + w0;
        size_t coff = ((size_t)b * 128 + w) * 512 + r;
        htc1[coff] = h0; htc1[coff + 512] = h1;
        htc2[coff] = l0; htc2[coff + 512] = l1;
    }
}

// ---------------------------------------------------------------------------
// dft (MFMA): X[128][4096] = F * htc^T, K=512, BK=64, depth-3 pipelined.
// grid (128 n-tiles of 32, 4 mc-tiles) = 512 blocks (2/CU). 4 waves, each
// one 16x16 frag (2 mc x 2 n wave layout).
// ---------------------------------------------------------------------------
__global__ __launch_bounds__(256) void dft_mfma(const u16* __restrict__ f1, const u16* __restrict__ f2,
        const u16* __restrict__ htc1, const u16* __restrict__ htc2,
        u16* __restrict__ x1, u16* __restrict__ x2) {
    __shared__ __align__(16) u16 A1[2][32 * 72], A2[2][32 * 72];
    __shared__ __align__(16) u16 B1[2][32 * 72], B2[2][32 * 72];
    int bx = blockIdx.x;                  // n = bx*32 + local; b = bx>>2, i0 = (bx&3)*32
    int mct = blockIdx.y * 32;
    int tid = threadIdx.x, wid = tid >> 6, l = tid & 63;
    int wm0 = (wid >> 1) * 16, wn0 = (wid & 1) * 16;
    int arow = l & 15, kgrp = (l >> 4) * 8;
    f32x4 acc = {0.f, 0.f, 0.f, 0.f};
    int pl = tid >> 7, row = (tid >> 2) & 31, sp = (tid & 3) * 16;
    const u16* asrc = (pl ? f2 : f1) + (size_t)(mct + row) * 512 + sp;
    const u16* bsrc = (pl ? htc2 : htc1)
                      + ((size_t)(bx >> 2) * 128 + (bx & 3) * 32 + row) * 512 + sp;
    int loff = row * 72 + sp;
    u16* ad0 = (pl ? A2[0] : A1[0]) + loff;  u16* ad1 = (pl ? A2[1] : A1[1]) + loff;
    u16* bd0 = (pl ? B2[0] : B1[0]) + loff;  u16* bd1 = (pl ? B2[1] : B1[1]) + loff;
    uint4 oA0, oA1, oB0, oB1, eA0, eA1, eB0, eB1;
    // chunk 0 -> buf0
    oA0 = *(const uint4*)(asrc);     oA1 = *(const uint4*)(asrc + 8);
    oB0 = *(const uint4*)(bsrc);     oB1 = *(const uint4*)(bsrc + 8);
    *(uint4*)ad0 = oA0; *(uint4*)(ad0 + 8) = oA1;
    *(uint4*)bd0 = oB0; *(uint4*)(bd0 + 8) = oB1;
    // chunk 1 -> O regs, chunk 2 -> E regs
    oA0 = *(const uint4*)(asrc + 64);  oA1 = *(const uint4*)(asrc + 72);
    oB0 = *(const uint4*)(bsrc + 64);  oB1 = *(const uint4*)(bsrc + 72);
    eA0 = *(const uint4*)(asrc + 128); eA1 = *(const uint4*)(asrc + 136);
    eB0 = *(const uint4*)(bsrc + 128); eB1 = *(const uint4*)(bsrc + 136);
    __syncthreads();
#define DFT_COMPUTE(BUF)                                                       \
    { _Pragma("unroll")                                                        \
      for (int kk = 0; kk < 64; kk += 32) {                                    \
        bf16x8 a1 = *(const bf16x8*)&A1[BUF][(wm0 + arow) * 72 + kk + kgrp];   \
        bf16x8 a2 = *(const bf16x8*)&A2[BUF][(wm0 + arow) * 72 + kk + kgrp];   \
        bf16x8 b1 = *(const bf16x8*)&B1[BUF][(wn0 + arow) * 72 + kk + kgrp];   \
        bf16x8 b2 = *(const bf16x8*)&B2[BUF][(wn0 + arow) * 72 + kk + kgrp];   \
        acc = MFMA16(a1, b1, acc);                                             \
        acc = MFMA16(a1, b2, acc);                                             \
        acc = MFMA16(a2, b1, acc);                                             \
      } }
    for (int k = 0; k < 8; k += 2) {
        DFT_COMPUTE(0)
        *(uint4*)ad1 = oA0; *(uint4*)(ad1 + 8) = oA1;
        *(uint4*)bd1 = oB0; *(uint4*)(bd1 + 8) = oB1;
        if (k < 5) {
            int ko = (k + 3) * 64;
            oA0 = *(const uint4*)(asrc + ko);      oA1 = *(const uint4*)(asrc + ko + 8);
            oB0 = *(const uint4*)(bsrc + ko);      oB1 = *(const uint4*)(bsrc + ko + 8);
        }
        __syncthreads();
        DFT_COMPUTE(1)
        if (k < 6) {
            *(uint4*)ad0 = eA0; *(uint4*)(ad0 + 8) = eA1;
            *(uint4*)bd0 = eB0; *(uint4*)(bd0 + 8) = eB1;
            if (k < 4) {
                int ko = (k + 4) * 64;
                eA0 = *(const uint4*)(asrc + ko);  eA1 = *(const uint4*)(asrc + ko + 8);
                eB0 = *(const uint4*)(bsrc + ko);  eB1 = *(const uint4*)(bsrc + ko + 8);
            }
        }
        __syncthreads();
    }
#undef DFT_COMPUTE
    int mcr = mct + wm0 + (l >> 4) * 4;
    int n0 = bx * 32 + wn0 + (l & 15);
#pragma unroll
    for (int j = 0; j < 4; j++) {
        size_t o0 = (size_t)(mcr + j) * 4096 + n0;
        x1[o0] = f2bf_hi(acc[j]); x2[o0] = f2bf_lo(acc[j]);
    }
}

// ---------------------------------------------------------------------------
// modemix (MFMA, single-barrier): per mode m: Y = W *c X, K=128 fully staged
// in LDS (8 slabs x 32 rows x 136, 69.6 KB). grid (64 m, 4 oq), 256 thr.
// ---------------------------------------------------------------------------
__global__ __launch_bounds__(256) void modemix_mfma(const u16* __restrict__ x1, const u16* __restrict__ x2,
        const u16* __restrict__ wr1, const u16* __restrict__ wr2,
        const u16* __restrict__ wi1, const u16* __restrict__ wi2,
        u16* __restrict__ y1, u16* __restrict__ y2, int layer) {
    __shared__ __align__(16) u16 POOL[8 * 32 * 136];   // slabs: WR1 WR2 WI1 WI2 XR1 XR2 XI1 XI2
    int m = blockIdx.x, oq = blockIdx.y;
    int tid = threadIdx.x, wid = tid >> 6, l = tid & 63;
    int wo0 = (wid >> 1) * 16, wb0 = (wid & 1) * 16;
    int arow = l & 15, kgrp = (l >> 4) * 8;
    size_t wbase = (((size_t)layer * 64 + m) * 128 + oq * 32) * 128;
    // stage ALL K=128: 16 uint4 per thread, compile-time slab per q
#pragma unroll
    for (int q = 0; q < 16; q++) {
        const int slab = q >> 1;
        int rr = ((q & 1) << 4) + (tid >> 4);
        int seg = tid & 15;
        const u16* src;
        if      (slab == 0) src = wr1 + wbase + (size_t)rr * 128 + seg * 8;
        else if (slab == 1) src = wr2 + wbase + (size_t)rr * 128 + seg * 8;
        else if (slab == 2) src = wi1 + wbase + (size_t)rr * 128 + seg * 8;
        else if (slab == 3) src = wi2 + wbase + (size_t)rr * 128 + seg * 8;
        else if (slab == 4) src = x1 + (size_t)m * 4096 + rr * 128 + seg * 8;
        else if (slab == 5) src = x2 + (size_t)m * 4096 + rr * 128 + seg * 8;
        else if (slab == 6) src = x1 + (size_t)(64 + m) * 4096 + rr * 128 + seg * 8;
        else                src = x2 + (size_t)(64 + m) * 4096 + rr * 128 + seg * 8;
        *(uint4*)&POOL[slab * 4352 + rr * 136 + seg * 8] = *(const uint4*)src;
    }
    __syncthreads();
    f32x4 ar = {0.f, 0.f, 0.f, 0.f}, ai = {0.f, 0.f, 0.f, 0.f};
    int aoB = (wo0 + arow) * 136 + kgrp;
    int boB = (wb0 + arow) * 136 + kgrp;
#pragma unroll
    for (int kg = 0; kg < 4; kg++) {
        int ao = aoB + kg * 32;
        int bo = boB + kg * 32;
        bf16x8 Wr1 = *(const bf16x8*)&POOL[0 * 4352 + ao];
        bf16x8 Wr2 = *(const bf16x8*)&POOL[1 * 4352 + ao];
        bf16x8 Wi1 = *(const bf16x8*)&POOL[2 * 4352 + ao];
        bf16x8 Wi2 = *(const bf16x8*)&POOL[3 * 4352 + ao];
        bf16x8 Xr1 = *(const bf16x8*)&POOL[4 * 4352 + bo];
        bf16x8 Xr2 = *(const bf16x8*)&POOL[5 * 4352 + bo];
        bf16x8 Xi1 = *(const bf16x8*)&POOL[6 * 4352 + bo];
        bf16x8 Xi2 = *(const bf16x8*)&POOL[7 * 4352 + bo];
        bf16x8 nWi1 = negbf(Wi1), nWi2 = negbf(Wi2);
        ar = MFMA16(Wr1, Xr1, ar); ar = MFMA16(Wr1, Xr2, ar); ar = MFMA16(Wr2, Xr1, ar);
        ar = MFMA16(nWi1, Xi1, ar); ar = MFMA16(nWi1, Xi2, ar); ar = MFMA16(nWi2, Xi1, ar);
        ai = MFMA16(Wi1, Xr1, ai); ai = MFMA16(Wi1, Xr2, ai); ai = MFMA16(Wi2, Xr1, ai);
        ai = MFMA16(Wr1, Xi1, ai); ai = MFMA16(Wr1, Xi2, ai); ai = MFMA16(Wr2, Xi1, ai);
    }
    int ob = oq * 32 + wo0 + (l >> 4) * 4;
    int bb = wb0 + (l & 15);
#pragma unroll
    for (int j = 0; j < 4; j++) {
        size_t o = ((size_t)bb * 128 + ob + j) * 128;
        y1[o + m] = f2bf_hi(ar[j]); y2[o + m] = f2bf_lo(ar[j]);
        y1[o + 64 + m] = f2bf_hi(ai[j]); y2[o + 64 + m] = f2bf_lo(ai[j]);
    }
}

// ---------------------------------------------------------------------------
// idft+conv (MFMA, depth-3): C[o][r] = [Y|CW](o,256)*[GT;ht](256,r)+bias,GELU.
// grid (8 rt, 2 ot, 32 b). T-transpose epilogue writes htc when wtr.
// ---------------------------------------------------------------------------
__global__ __launch_bounds__(256) void idft_conv_mfma(const u16* __restrict__ y1, const u16* __restrict__ y2,
        const u16* __restrict__ gt1, const u16* __restrict__ gt2,
        const u16* __restrict__ hc1, const u16* __restrict__ hc2,
        const u16* __restrict__ cw1, const u16* __restrict__ cw2,
        const float* __restrict__ conv_b,
        u16* __restrict__ hn1, u16* __restrict__ hn2,
        u16* __restrict__ htc1, u16* __restrict__ htc2, int layer, int wtr) {
    __shared__ __align__(16) u16 A1[2][2560], A2[2][2560];
    __shared__ __align__(16) u16 B1[2][2560], B2[2][2560];
    __shared__ __align__(16) u16 T1[64 * 66], T2[64 * 66];
    int rt = blockIdx.x * 64, ot = blockIdx.y * 64, b = blockIdx.z;
    int tid = threadIdx.x, wid = tid >> 6, l = tid & 63;
    int wo0 = (wid >> 1) * 32, wr0 = (wid & 1) * 32;
    int arow = (l & 15), kgrp = (l >> 4) * 8;
    int srow = (tid >> 2) & 63, sseg = tid & 3;
    int soff = srow * 40 + sseg * 8;
    const u16* ya = y1 + ((size_t)b * 128 + ot + srow) * 128 + sseg * 8;
    const u16* yb = y2 + ((size_t)b * 128 + ot + srow) * 128 + sseg * 8;
    const u16* ca = cw1 + ((size_t)layer * 128 + ot + srow) * 128 + sseg * 8;
    const u16* cb = cw2 + ((size_t)layer * 128 + ot + srow) * 128 + sseg * 8;
    const u16* ga = gt1 + (size_t)(rt + srow) * 128 + sseg * 8;
    const u16* gb = gt2 + (size_t)(rt + srow) * 128 + sseg * 8;
    const u16* ha = hc1 + ((size_t)b * 512 + rt + srow) * 128 + sseg * 8;
    const u16* hb = hc2 + ((size_t)b * 512 + rt + srow) * 128 + sseg * 8;
    f32x4 acc[2][2] = {{{0.f,0.f,0.f,0.f},{0.f,0.f,0.f,0.f}},{{0.f,0.f,0.f,0.f},{0.f,0.f,0.f,0.f}}};
    uint4 raO0, raO1, rbO0, rbO1, raE0, raE1, rbE0, rbE1;
#define IDFT_LOAD(chk, Ra0, Ra1, Rb0, Rb1)                                    \
    {   int k0_ = ((chk) & 3) * 32;                                           \
        if ((chk) < 4) {                                                      \
            Ra0 = *(const uint4*)(ya + k0_); Ra1 = *(const uint4*)(yb + k0_); \
            Rb0 = *(const uint4*)(ga + k0_); Rb1 = *(const uint4*)(gb + k0_); \
        } else {                                                              \
            Ra0 = *(const uint4*)(ca + k0_); Ra1 = *(const uint4*)(cb + k0_); \
            Rb0 = *(const uint4*)(ha + k0_); Rb1 = *(const uint4*)(hb + k0_); \
        } }
#define IDFT_STORE(BUF, Ra0, Ra1, Rb0, Rb1)                                   \
    {   *(uint4*)(A1[BUF] + soff) = Ra0; *(uint4*)(A2[BUF] + soff) = Ra1;     \
        *(uint4*)(B1[BUF] + soff) = Rb0; *(uint4*)(B2[BUF] + soff) = Rb1; }
#define IDFT_COMPUTE(BUF)                                                     \
    {   bf16x8 bfr[2][2];                                                     \
        _Pragma("unroll")                                                     \
        for (int rf = 0; rf < 2; rf++) {                                      \
            bfr[rf][0] = *(const bf16x8*)&B1[BUF][(wr0 + rf * 16 + arow) * 40 + kgrp]; \
            bfr[rf][1] = *(const bf16x8*)&B2[BUF][(wr0 + rf * 16 + arow) * 40 + kgrp]; \
        }                                                                     \
        _Pragma("unroll")                                                     \
        for (int of = 0; of < 2; of++) {                                      \
            bf16x8 a1 = *(const bf16x8*)&A1[BUF][(wo0 + of * 16 + arow) * 40 + kgrp]; \
            bf16x8 a2 = *(const bf16x8*)&A2[BUF][(wo0 + of * 16 + arow) * 40 + kgrp]; \
            _Pragma("unroll")                                                 \
            for (int rf = 0; rf < 2; rf++) {                                  \
                acc[of][rf] = MFMA16(a1, bfr[rf][0], acc[of][rf]);            \
                acc[of][rf] = MFMA16(a1, bfr[rf][1], acc[of][rf]);            \
                acc[of][rf] = MFMA16(a2, bfr[rf][0], acc[of][rf]);            \
            }                                                                 \
        } }
    IDFT_LOAD(0, raO0, raO1, rbO0, rbO1)
    IDFT_STORE(0, raO0, raO1, rbO0, rbO1)
    IDFT_LOAD(1, raO0, raO1, rbO0, rbO1)
    IDFT_LOAD(2, raE0, raE1, rbE0, rbE1)
    __syncthreads();
    for (int k = 0; k < 8; k += 2) {
        IDFT_COMPUTE(0)
        IDFT_STORE(1, raO0, raO1, rbO0, rbO1)
        if (k < 5) IDFT_LOAD(k + 3, raO0, raO1, rbO0, rbO1)
        __syncthreads();
        IDFT_COMPUTE(1)
        if (k < 6) {
            IDFT_STORE(0, raE0, raE1, rbE0, rbE1)
            if (k < 4) IDFT_LOAD(k + 4, raE0, raE1, rbE0, rbE1)
        }
        __syncthreads();
    }
#undef IDFT_LOAD
#undef IDFT_STORE
#undef IDFT_COMPUTE
#pragma unroll
    for (int of = 0; of < 2; of++) {
        int obl = wo0 + of * 16 + (l >> 4) * 4;
        int ob = ot + obl;
#pragma unroll
        for (int rf = 0; rf < 2; rf++) {
            int rloc = wr0 + rf * 16 + (l & 15);
            int r = rt + rloc;
            float v0 = gelu_exact(acc[of][rf][0] + conv_b[layer * 128 + ob + 0]);
            float v1 = gelu_exact(acc[of][rf][1] + conv_b[layer * 128 + ob + 1]);
            float v2 = gelu_exact(acc[of][rf][2] + conv_b[layer * 128 + ob + 2]);
            float v3 = gelu_exact(acc[of][rf][3] + conv_b[layer * 128 + ob + 3]);
            ushort4 hv, lv;
            hv.x = f2bf_hi(v0); hv.y = f2bf_hi(v1); hv.z = f2bf_hi(v2); hv.w = f2bf_hi(v3);
            lv.x = f2bf_lo(v0); lv.y = f2bf_lo(v1); lv.z = f2bf_lo(v2); lv.w = f2bf_lo(v3);
            size_t off = ((size_t)b * 512 + r) * 128 + ob;
            *(ushort4*)&hn1[off] = hv;
            *(ushort4*)&hn2[off] = lv;
            if (wtr) {
                T1[(obl + 0) * 66 + rloc] = hv.x; T1[(obl + 1) * 66 + rloc] = hv.y;
                T1[(obl + 2) * 66 + rloc] = hv.z; T1[(obl + 3) * 66 + rloc] = hv.w;
                T2[(obl + 0) * 66 + rloc] = lv.x; T2[(obl + 1) * 66 + rloc] = lv.y;
                T2[(obl + 2) * 66 + rloc] = lv.z; T2[(obl + 3) * 66 + rloc] = lv.w;
            }
        }
    }
    if (wtr) {
        __syncthreads();
#pragma unroll
        for (int q = 0; q < 8; q++) {
            int t = tid + q * 256;
            int o = t >> 5, ru = t & 31;
            u32 vh = *(const u32*)&T1[o * 66 + ru * 2];
            u32 vl = *(const u32*)&T2[o * 66 + ru * 2];
            size_t off = ((size_t)b * 128 + ot + o) * 512 + rt + ru * 2;
            *(u32*)&htc1[off] = vh;
            *(u32*)&htc2[off] = vl;
        }
    }
}

// ---------------------------------------------------------------------------
// head (MFMA) + fused fc0 for next step. grid 256 blocks, 4 waves x 16 rows.
// acc[16] fully static-indexed (full unrolls) -> register resident.
// ---------------------------------------------------------------------------
__global__ __launch_bounds__(256) void head_mfma(const u16* __restrict__ ht1, const u16* __restrict__ ht2,
        const u16* __restrict__ f11, const u16* __restrict__ f12,
        const float* __restrict__ fc1_b, const float* __restrict__ fc2_w,
        const float* __restrict__ fc2_b,
        const float* __restrict__ t_grid, const float* __restrict__ fc0_w,
        const float* __restrict__ fc0_b,
        float* __restrict__ seq, float* __restrict__ preds,
        u16* __restrict__ nht1, u16* __restrict__ nht2,
        u16* __restrict__ nhtc1, u16* __restrict__ nhtc2,
        int step, int do_fc0) {
    __shared__ __align__(16) u16 POOL[25600];     // 51.2 KB, aliased in epilogue
    __shared__ float fc2s[256], fc1bs[256];
    u16* HA1 = POOL;                // 256*40
    u16* HA2 = POOL + 10240;
    u16* HB1 = POOL + 20480;        // 64*40
    u16* HB2 = POOL + 23040;
    int blk = blockIdx.x;
    int b = blk >> 3, r0 = (blk & 7) * 64;
    int tid = threadIdx.x, wid = tid >> 6, l = tid & 63;
    fc2s[tid] = fc2_w[tid];
    fc1bs[tid] = fc1_b[tid];
    int arow = l & 15, kgrp = (l >> 4) * 8;
    f32x4 acc[16];
#pragma unroll
    for (int jf = 0; jf < 16; jf++) acc[jf] = (f32x4){0.f, 0.f, 0.f, 0.f};
    for (int k0 = 0; k0 < 128; k0 += 32) {
        __syncthreads();
#pragma unroll
        for (int q = 0; q < 8; q++) {
            int t = tid + q * 256;
            int pl = t >> 10, j = (t >> 2) & 255, seg = t & 3;
            const u16* src = (pl ? f12 : f11) + (size_t)j * 128 + k0 + seg * 8;
            *(uint4*)((pl ? HA2 : HA1) + j * 40 + seg * 8) = *(const uint4*)src;
        }
#pragma unroll
        for (int q = 0; q < 2; q++) {
            int t = tid + q * 256;
            int pl = t >> 8, rr = (t >> 2) & 63, seg = t & 3;
            const u16* src = (pl ? ht2 : ht1) + ((size_t)b * 512 + r0 + rr) * 128 + k0 + seg * 8;
            *(uint4*)((pl ? HB2 : HB1) + rr * 40 + seg * 8) = *(const uint4*)src;
        }
        __syncthreads();
        int bo = (wid * 16 + arow) * 40 + kgrp;
        bf16x8 b1 = *(const bf16x8*)&HB1[bo];
        bf16x8 b2 = *(const bf16x8*)&HB2[bo];
#pragma unroll
        for (int jf = 0; jf < 16; jf++) {
            int ao = (jf * 16 + arow) * 40 + kgrp;
            bf16x8 a1 = *(const bf16x8*)&HA1[ao];
            bf16x8 a2 = *(const bf16x8*)&HA2[ao];
            acc[jf] = MFMA16(a1, b1, acc[jf]);
            acc[jf] = MFMA16(a1, b2, acc[jf]);
            acc[jf] = MFMA16(a2, b1, acc[jf]);
        }
    }
    __syncthreads();   // all POOL reads done; safe to alias below
    float dx = 0.0f;
#pragma unroll
    for (int jf = 0; jf < 16; jf++) {
        int jbase = jf * 16 + (l >> 4) * 4;
#pragma unroll
        for (int jj = 0; jj < 4; jj++) {
            int j = jbase + jj;
            dx += gelu_exact(acc[jf][jj] + fc1bs[j]) * fc2s[j];
        }
    }
    dx += __shfl_xor(dx, 16);
    dx += __shfl_xor(dx, 32);
    bool zlane = ((l >> 4) == 0);
    int rml = wid * 16 + arow;
    float zn = 0.0f;
    if (zlane) {
        int r = r0 + rml;
        zn = seq[((size_t)b * SEQROWS + step + 23) * NR + r] + dx + fc2_b[0];
        seq[((size_t)b * SEQROWS + step + 24) * NR + r] = zn;
        preds[((size_t)b * NSTEPS + step) * NR + r] = zn;
    }
    if (!do_fc0) return;
    float* win = (float*)POOL;                 // [24][64]
    float* wl  = (float*)POOL + 2048;          // [28][128]
    float* bl  = (float*)POOL + 2048 + 3584;   // [128]
    for (int t = tid; t < 23 * 64; t += 256) {
        int tr = t >> 6, c = t & 63;
        win[tr * 64 + c] = seq[((size_t)b * SEQROWS + step + 1 + tr) * NR + r0 + c];
    }
    for (int t = tid; t < 28 * 128; t += 256) wl[t] = fc0_w[t];
    if (tid < 128) bl[tid] = fc0_b[tid];
    if (zlane) win[23 * 64 + rml] = zn;
    __syncthreads();
    int lane = tid & 63, wq = tid >> 6;
    int r = r0 + lane;
    float sv[24];
#pragma unroll
    for (int t = 0; t < 24; t++) sv[t] = win[t * 64 + lane];
    float tt = t_grid[b * 24 + 23] + (float)(step + 2);
    float ang24 = 6.28318530717958647692f * tt * (1.0f / 24.0f);
    float ang168 = 6.28318530717958647692f * tt * (1.0f / 168.0f);
    float s24 = sinf(ang24), c24 = cosf(ang24), s168 = sinf(ang168);
    float xc = (float)r * (1.0f / 511.0f);
    size_t rowoff = ((size_t)b * NR + r) * NW;
#pragma unroll 2
    for (int w0 = 0; w0 < 32; w0 += 2) {
        float acc2[2];
#pragma unroll
        for (int q = 0; q < 2; q++) {
            int w = wq * 32 + w0 + q;
            float a = bl[w];
#pragma unroll
            for (int t = 0; t < 24; t++) a += sv[t] * wl[t * 128 + w];
            a += s24 * wl[24 * 128 + w] + c24 * wl[25 * 128 + w]
               + s168 * wl[26 * 128 + w] + xc * wl[27 * 128 + w];
            acc2[q] = a;
        }
        u16 h0 = f2bf_hi(acc2[0]), h1 = f2bf_hi(acc2[1]);
        u16 l0 = f2bf_lo(acc2[0]), l1 = f2bf_lo(acc2[1]);
        size_t off = rowoff + wq * 32 + w0;
        *(u32*)&nht1[off] = (u32)h0 | ((u32)h1 << 16);
        *(u32*)&nht2[off] = (u32)l0 | ((u32)l1 << 16);
        int w = wq * 32 + w0;
        size_t coff = ((size_t)b * 128 + w) * 512 + r;
        nhtc1[coff] = h0; nhtc1[coff + 512] = h1;
        nhtc2[coff] = l0; nhtc2[coff + 512] = l1;
    }
}

// ---------------------------------------------------------------------------
extern "C" void kernel_launch(void* const* d_in, const int* in_sizes, int n_in,
                              void* d_out, int out_size, void* d_ws, size_t ws_size,
                              hipStream_t stream) {
    (void)in_sizes; (void)n_in; (void)out_size; (void)ws_size;
    const float* z       = (const float*)d_in[0];
    const float* t_grid  = (const float*)d_in[1];
    const float* fc0_w   = (const float*)d_in[2];
    const float* fc0_b   = (const float*)d_in[3];
    const float* spec_wr = (const float*)d_in[4];
    const float* spec_wi = (const float*)d_in[5];
    const float* conv_w  = (const float*)d_in[6];
    const float* conv_b  = (const float*)d_in[7];
    const float* fc1_w   = (const float*)d_in[8];
    const float* fc1_b   = (const float*)d_in[9];
    const float* fc2_w   = (const float*)d_in[10];
    const float* fc2_b   = (const float*)d_in[11];
    float* preds = (float*)d_out;

    char* p = (char*)d_ws;
    float* seq = (float*)p;  p += (size_t)NB * SEQROWS * NR * 4;
    u16* ht1 = (u16*)p;  p += (size_t)2 * NB * NR * NW * 2;   // [2 buf][b][r][c] hi
    u16* ht2 = (u16*)p;  p += (size_t)2 * NB * NR * NW * 2;   // lo
    u16* htc1 = (u16*)p; p += (size_t)NB * NW * NR * 2;       // [b][c][r] hi
    u16* htc2 = (u16*)p; p += (size_t)NB * NW * NR * 2;       // lo
    u16* x1  = (u16*)p;  p += (size_t)128 * 4096 * 2;
    u16* x2  = (u16*)p;  p += (size_t)128 * 4096 * 2;
    u16* y1  = (u16*)p;  p += (size_t)NB * NW * 128 * 2;
    u16* y2  = (u16*)p;  p += (size_t)NB * NW * 128 * 2;
    u16* f1  = (u16*)p;  p += (size_t)128 * 512 * 2;
    u16* f2  = (u16*)p;  p += (size_t)128 * 512 * 2;
    u16* gt1 = (u16*)p;  p += (size_t)512 * 128 * 2;
    u16* gt2 = (u16*)p;  p += (size_t)512 * 128 * 2;
    u16* wr1 = (u16*)p;  p += (size_t)NLAY * NM * NW * NW * 2;
    u16* wr2 = (u16*)p;  p += (size_t)NLAY * NM * NW * NW * 2;
    u16* wi1 = (u16*)p;  p += (size_t)NLAY * NM * NW * NW * 2;
    u16* wi2 = (u16*)p;  p += (size_t)NLAY * NM * NW * NW * 2;
    u16* cw1 = (u16*)p;  p += (size_t)NLAY * NW * NW * 2;
    u16* cw2 = (u16*)p;  p += (size_t)NLAY * NW * NW * 2;
    u16* f11 = (u16*)p;  p += (size_t)256 * 128 * 2;
    u16* f12 = (u16*)p;  p += (size_t)256 * 128 * 2;

    const size_t htplane = (size_t)NB * NR * NW;

    build_tables_planes<<<256, 256, 0, stream>>>(f1, f2, gt1, gt2);
    prep_specw<<<512, 256, 0, stream>>>(spec_wr, spec_wi, wr1, wr2, wi1, wi2);
    prep_cw<<<256, 256, 0, stream>>>(conv_w, cw1, cw2);
    prep_fc1t<<<128, 256, 0, stream>>>(fc1_w, f11, f12);
    init_seq_kernel<<<(NB * NTH * NR) / 256, 256, 0, stream>>>(z, seq);

    for (int step = 0; step < NSTEPS; step++) {
        if (step == 0) {
            fc0_kernel<<<dim3(8, 32), 256, 0, stream>>>(seq, t_grid, fc0_w, fc0_b,
                                                        ht1, ht2, htc1, htc2, step);
        }
        int cur = 0;
        for (int l = 0; l < NLAY; l++) {
            const u16* hc1 = ht1 + (size_t)cur * htplane;
            const u16* hc2 = ht2 + (size_t)cur * htplane;
            u16* hn1 = ht1 + (size_t)(cur ^ 1) * htplane;
            u16* hn2 = ht2 + (size_t)(cur ^ 1) * htplane;
            dft_mfma<<<dim3(128, 4), 256, 0, stream>>>(f1, f2, htc1, htc2, x1, x2);
            modemix_mfma<<<dim3(64, 4), 256, 0, stream>>>(x1, x2, wr1, wr2, wi1, wi2,
                                                          y1, y2, l);
            idft_conv_mfma<<<dim3(8, 2, 32), 256, 0, stream>>>(y1, y2, gt1, gt2,
                                                               hc1, hc2, cw1, cw2,
                                                               conv_b, hn1, hn2,
                                                               htc1, htc2, l, (l < 3) ? 1 : 0);
            cur ^= 1;
        }
        head_mfma<<<256, 256, 0, stream>>>(ht1, ht2, f11, f12, fc1_b, fc2_w, fc2_b,
                                           t_grid, fc0_w, fc0_b, seq, preds,
                                           ht1, ht2, htc1, htc2,
                                           step, (step < NSTEPS - 1) ? 1 : 0);
    }
}

// Round 10
// 1809.211 us; speedup vs baseline: 1.0009x; 1.0009x over previous
//
#include <hip/hip_runtime.h>
#include <math.h>

// LatentFNO: B=32, T=24, R=512, W=128, M=64 modes, 4 layers, 12 steps.
// Round 9: spectral dispatch latency attack (arithmetic unchanged, bitwise
// identical): (a) dft re-tiled 32x32 -> 512 blocks (2/CU overlap), BK=64
// (16 barriers vs 32); (b) modemix stages ALL of K=128 in 69.6 KB LDS ->
// ONE barrier (was 8). idft/head unchanged from round 8.
// Math: exact 3-term bf16 split (A1B1+A1B2+A2B1).

#define NB 32
#define NR 512
#define NW 128
#define NM 64
#define NTH 24
#define NLAY 4
#define NSTEPS 12
#define SEQROWS 36

typedef unsigned short u16;
typedef unsigned int u32;
typedef __attribute__((ext_vector_type(8))) short bf16x8;
typedef __attribute__((ext_vector_type(4))) float f32x4;
#define MFMA16(a, b, c) __builtin_amdgcn_mfma_f32_16x16x32_bf16((a), (b), (c), 0, 0, 0)

__device__ __forceinline__ float gelu_exact(float x) {
    return 0.5f * x * (1.0f + erff(x * 0.70710678118654752f));
}
__device__ __forceinline__ float bf2f(u16 u) {
    union { u32 i; float f; } v; v.i = ((u32)u) << 16; return v.f;
}
__device__ __forceinline__ u16 f2bf_hi(float x) {
    union { float f; u32 i; } v; v.f = x; return (u16)(v.i >> 16);
}
__device__ __forceinline__ u16 f2bf_lo(float x) {
    float h = bf2f(f2bf_hi(x));
    return f2bf_hi(x - h);
}
__device__ __forceinline__ bf16x8 negbf(bf16x8 a) {
#pragma unroll
    for (int i = 0; i < 8; i++) a[i] ^= (short)0x8000;
    return a;
}

// ---------------------------------------------------------------------------
// Tables: F planes [mc=128][r=512]; GT planes [r=512][mc=128].
// ---------------------------------------------------------------------------
__global__ void build_tables_planes(u16* __restrict__ f1, u16* __restrict__ f2,
                                    u16* __restrict__ gt1, u16* __restrict__ gt2) {
    int idx = blockIdx.x * 256 + threadIdx.x;   // 65536: mc*512 + r
    int mc = idx >> 9, r = idx & 511, m = mc & 63;
    int p = (m * r) & 511;
    float a = (float)p * (1.0f / 256.0f);
    float c = cospif(a), s = sinpif(a);
    float Fv = (mc < 64) ? c : -s;
    float cm = (m == 0) ? (1.0f / 512.0f) : (2.0f / 512.0f);
    float Gv = (mc < 64) ? cm * c : ((m == 0) ? 0.0f : -cm * s);
    f1[idx] = f2bf_hi(Fv); f2[idx] = f2bf_lo(Fv);
    size_t g = (size_t)r * 128 + mc;
    gt1[g] = f2bf_hi(Gv); gt2[g] = f2bf_lo(Gv);
}

// spec_w (l,i,o,m) -> planes [l][m][o][i] hi/lo, coalesced both directions.
__global__ __launch_bounds__(256) void prep_specw(const float* __restrict__ wr, const float* __restrict__ wi,
                           u16* __restrict__ wr1, u16* __restrict__ wr2,
                           u16* __restrict__ wi1, u16* __restrict__ wi2) {
    __shared__ float tile[128][65];
    int l = blockIdx.x >> 7, o = blockIdx.x & 127;
    int tid = threadIdx.x;
    size_t sbase = (size_t)l * 1048576 + (size_t)o * 64;
    size_t dbase = (size_t)l * 64 * 16384 + (size_t)o * 128;
    for (int pass = 0; pass < 2; pass++) {
        const float* src = pass ? wi : wr;
        u16* d1 = pass ? wi1 : wr1;
        u16* d2 = pass ? wi2 : wr2;
        if (pass) __syncthreads();
        for (int e = tid; e < 8192; e += 256) {
            int i = e >> 6, m = e & 63;
            tile[i][m] = src[sbase + (size_t)i * 8192 + m];
        }
        __syncthreads();
        for (int e = tid; e < 4096; e += 256) {
            int m = e >> 6, i2 = (e & 63) * 2;
            float v0 = tile[i2][m], v1 = tile[i2 + 1][m];
            u32 hh = (u32)f2bf_hi(v0) | ((u32)f2bf_hi(v1) << 16);
            u32 ll = (u32)f2bf_lo(v0) | ((u32)f2bf_lo(v1) << 16);
            size_t d = dbase + (size_t)m * 16384 + i2;
            *(u32*)&d1[d] = hh;
            *(u32*)&d2[d] = ll;
        }
    }
}

__global__ void prep_cw(const float* __restrict__ cw, u16* __restrict__ c1, u16* __restrict__ c2) {
    int idx = blockIdx.x * 256 + threadIdx.x;   // 65536
    float v = cw[idx];
    c1[idx] = f2bf_hi(v); c2[idx] = f2bf_lo(v);
}

// fc1_w [c=128][j=256] -> fc1t planes [j][c] hi/lo
__global__ void prep_fc1t(const float* __restrict__ fc1_w,
                          u16* __restrict__ f11, u16* __restrict__ f12) {
    int idx = blockIdx.x * 256 + threadIdx.x;   // 32768: j*128 + c
    int j = idx >> 7, c = idx & 127;
    float v = fc1_w[(size_t)c * 256 + j];
    f11[idx] = f2bf_hi(v); f12[idx] = f2bf_lo(v);
}

__global__ void init_seq_kernel(const float* __restrict__ z, float* __restrict__ seq) {
    int idx = blockIdx.x * 256 + threadIdx.x;    // < 32*24*512
    int b = idx / (NTH * NR);
    int rem = idx - b * (NTH * NR);
    seq[(size_t)b * SEQROWS * NR + rem] = z[idx];
}

// ---------------------------------------------------------------------------
// fc0 (fp32), step 0 only: writes ht[b][r][c] AND htc[b][c][r] planes.
// ---------------------------------------------------------------------------
__global__ __launch_bounds__(256) void fc0_kernel(const float* __restrict__ seq,
        const float* __restrict__ t_grid, const float* __restrict__ fc0_w,
        const float* __restrict__ fc0_b, u16* __restrict__ ht1, u16* __restrict__ ht2,
        u16* __restrict__ htc1, u16* __restrict__ htc2, int step) {
    __shared__ float wlds[28 * 128];
    __shared__ float blds[128];
    int b = blockIdx.y, rblk = blockIdx.x;
    int tid = threadIdx.x;
    for (int t = tid; t < 28 * 128; t += 256) wlds[t] = fc0_w[t];
    if (tid < 128) blds[tid] = fc0_b[tid];
    __syncthreads();
    int lane = tid & 63, wq = tid >> 6;
    int r = rblk * 64 + lane;
    float sv[24];
    const float* sp = seq + ((size_t)b * SEQROWS + step) * NR + r;
#pragma unroll
    for (int t = 0; t < 24; t++) sv[t] = sp[(size_t)t * NR];
    float tt = t_grid[b * 24 + 23] + (float)(step + 1);
    float ang24 = 6.28318530717958647692f * tt * (1.0f / 24.0f);
    float ang168 = 6.28318530717958647692f * tt * (1.0f / 168.0f);
    float s24 = sinf(ang24), c24 = cosf(ang24), s168 = sinf(ang168);
    float xc = (float)r * (1.0f / 511.0f);
    size_t rowoff = ((size_t)b * NR + r) * NW;
#pragma unroll 2
    for (int w0 = 0; w0 < 32; w0 += 2) {
        float acc2[2];
#pragma unroll
        for (int q = 0; q < 2; q++) {
            int w = wq * 32 + w0 + q;
            float acc = blds[w];
#pragma unroll
            for (int t = 0; t < 24; t++) acc += sv[t] * wlds[t * 128 + w];
            acc += s24 * wlds[24 * 128 + w] + c24 * wlds[25 * 128 + w]
                 + s168 * wlds[26 * 128 + w] + xc * wlds[27 * 128 + w];
            acc2[q] = acc;
        }
        u16 h0 = f2bf_hi(acc2[0]), h1 = f2bf_hi(acc2[1]);
        u16 l0 = f2bf_lo(acc2[0]), l1 = f2bf_lo(acc2[1]);
        size_t off = rowoff + wq * 32 + w0;
        *(u32*)&ht1[off] = (u32)h0 | ((u32)h1 << 16);
        *(u32*)&ht2[off] = (u32)l0 | ((u32)l1 << 16);
        int w = wq * 32 + w0;
        size_t coff = ((size_t)b * 128 + w) * 512 + r;
        htc1[coff] = h0; htc1[coff + 512] = h1;
        htc2[coff] = l0; htc2[coff + 512] = l1;
    }
}

// ---------------------------------------------------------------------------
// dft (MFMA): X[128][4096] = F * htc^T, K=512, BK=64, depth-3 pipelined.
// grid (128 n-tiles of 32, 4 mc-tiles) = 512 blocks (2/CU). 4 waves, each
// one 16x16 frag (2 mc x 2 n wave layout).
// ---------------------------------------------------------------------------
__global__ __launch_bounds__(256) void dft_mfma(const u16* __restrict__ f1, const u16* __restrict__ f2,
        const u16* __restrict__ htc1, const u16* __restrict__ htc2,
        u16* __restrict__ x1, u16* __restrict__ x2) {
    __shared__ __align__(16) u16 A1[2][32 * 72], A2[2][32 * 72];
    __shared__ __align__(16) u16 B1[2][32 * 72], B2[2][32 * 72];
    int bx = blockIdx.x;                  // n = bx*32 + local; b = bx>>2, i0 = (bx&3)*32
    int mct = blockIdx.y * 32;
    int tid = threadIdx.x, wid = tid >> 6, l = tid & 63;
    int wm0 = (wid >> 1) * 16, wn0 = (wid & 1) * 16;
    int arow = l & 15, kgrp = (l >> 4) * 8;
    f32x4 acc = {0.f, 0.f, 0.f, 0.f};
    int pl = tid >> 7, row = (tid >> 2) & 31, sp = (tid & 3) * 16;
    const u16* asrc = (pl ? f2 : f1) + (size_t)(mct + row) * 512 + sp;
    const u16* bsrc = (pl ? htc2 : htc1)
                      + ((size_t)(bx >> 2) * 128 + (bx & 3) * 32 + row) * 512 + sp;
    int loff = row * 72 + sp;
    u16* ad0 = (pl ? A2[0] : A1[0]) + loff;  u16* ad1 = (pl ? A2[1] : A1[1]) + loff;
    u16* bd0 = (pl ? B2[0] : B1[0]) + loff;  u16* bd1 = (pl ? B2[1] : B1[1]) + loff;
    uint4 oA0, oA1, oB0, oB1, eA0, eA1, eB0, eB1;
    // chunk 0 -> buf0
    oA0 = *(const uint4*)(asrc);     oA1 = *(const uint4*)(asrc + 8);
    oB0 = *(const uint4*)(bsrc);     oB1 = *(const uint4*)(bsrc + 8);
    *(uint4*)ad0 = oA0; *(uint4*)(ad0 + 8) = oA1;
    *(uint4*)bd0 = oB0; *(uint4*)(bd0 + 8) = oB1;
    // chunk 1 -> O regs, chunk 2 -> E regs
    oA0 = *(const uint4*)(asrc + 64);  oA1 = *(const uint4*)(asrc + 72);
    oB0 = *(const uint4*)(bsrc + 64);  oB1 = *(const uint4*)(bsrc + 72);
    eA0 = *(const uint4*)(asrc + 128); eA1 = *(const uint4*)(asrc + 136);
    eB0 = *(const uint4*)(bsrc + 128); eB1 = *(const uint4*)(bsrc + 136);
    __syncthreads();
#define DFT_COMPUTE(BUF)                                                       \
    { _Pragma("unroll")                                                        \
      for (int kk = 0; kk < 64; kk += 32) {                                    \
        bf16x8 a1 = *(const bf16x8*)&A1[BUF][(wm0 + arow) * 72 + kk + kgrp];   \
        bf16x8 a2 = *(const bf16x8*)&A2[BUF][(wm0 + arow) * 72 + kk + kgrp];   \
        bf16x8 b1 = *(const bf16x8*)&B1[BUF][(wn0 + arow) * 72 + kk + kgrp];   \
        bf16x8 b2 = *(const bf16x8*)&B2[BUF][(wn0 + arow) * 72 + kk + kgrp];   \
        acc = MFMA16(a1, b1, acc);                                             \
        acc = MFMA16(a1, b2, acc);                                             \
        acc = MFMA16(a2, b1, acc);                                             \
      } }
    for (int k = 0; k < 8; k += 2) {
        DFT_COMPUTE(0)
        *(uint4*)ad1 = oA0; *(uint4*)(ad1 + 8) = oA1;
        *(uint4*)bd1 = oB0; *(uint4*)(bd1 + 8) = oB1;
        if (k < 5) {
            int ko = (k + 3) * 64;
            oA0 = *(const uint4*)(asrc + ko);      oA1 = *(const uint4*)(asrc + ko + 8);
            oB0 = *(const uint4*)(bsrc + ko);      oB1 = *(const uint4*)(bsrc + ko + 8);
        }
        __syncthreads();
        DFT_COMPUTE(1)
        if (k < 6) {
            *(uint4*)ad0 = eA0; *(uint4*)(ad0 + 8) = eA1;
            *(uint4*)bd0 = eB0; *(uint4*)(bd0 + 8) = eB1;
            if (k < 4) {
                int ko = (k + 4) * 64;
                eA0 = *(const uint4*)(asrc + ko);  eA1 = *(const uint4*)(asrc + ko + 8);
                eB0 = *(const uint4*)(bsrc + ko);  eB1 = *(const uint4*)(bsrc + ko + 8);
            }
        }
        __syncthreads();
    }
#undef DFT_COMPUTE
    int mcr = mct + wm0 + (l >> 4) * 4;
    int n0 = bx * 32 + wn0 + (l & 15);
#pragma unroll
    for (int j = 0; j < 4; j++) {
        size_t o0 = (size_t)(mcr + j) * 4096 + n0;
        x1[o0] = f2bf_hi(acc[j]); x2[o0] = f2bf_lo(acc[j]);
    }
}

// ---------------------------------------------------------------------------
// modemix (MFMA, single-barrier): per mode m: Y = W *c X, K=128 fully staged
// in LDS (8 slabs x 32 rows x 136, 69.6 KB). grid (64 m, 4 oq), 256 thr.
// ---------------------------------------------------------------------------
__global__ __launch_bounds__(256) void modemix_mfma(const u16* __restrict__ x1, const u16* __restrict__ x2,
        const u16* __restrict__ wr1, const u16* __restrict__ wr2,
        const u16* __restrict__ wi1, const u16* __restrict__ wi2,
        u16* __restrict__ y1, u16* __restrict__ y2, int layer) {
    __shared__ __align__(16) u16 POOL[8 * 32 * 136];   // slabs: WR1 WR2 WI1 WI2 XR1 XR2 XI1 XI2
    int m = blockIdx.x, oq = blockIdx.y;
    int tid = threadIdx.x, wid = tid >> 6, l = tid & 63;
    int wo0 = (wid >> 1) * 16, wb0 = (wid & 1) * 16;
    int arow = l & 15, kgrp = (l >> 4) * 8;
    size_t wbase = (((size_t)layer * 64 + m) * 128 + oq * 32) * 128;
    // stage ALL K=128: 16 uint4 per thread, compile-time slab per q
#pragma unroll
    for (int q = 0; q < 16; q++) {
        const int slab = q >> 1;
        int rr = ((q & 1) << 4) + (tid >> 4);
        int seg = tid & 15;
        const u16* src;
        if      (slab == 0) src = wr1 + wbase + (size_t)rr * 128 + seg * 8;
        else if (slab == 1) src = wr2 + wbase + (size_t)rr * 128 + seg * 8;
        else if (slab == 2) src = wi1 + wbase + (size_t)rr * 128 + seg * 8;
        else if (slab == 3) src = wi2 + wbase + (size_t)rr * 128 + seg * 8;
        else if (slab == 4) src = x1 + (size_t)m * 4096 + rr * 128 + seg * 8;
        else if (slab == 5) src = x2 + (size_t)m * 4096 + rr * 128 + seg * 8;
        else if (slab == 6) src = x1 + (size_t)(64 + m) * 4096 + rr * 128 + seg * 8;
        else                src = x2 + (size_t)(64 + m) * 4096 + rr * 128 + seg * 8;
        *(uint4*)&POOL[slab * 4352 + rr * 136 + seg * 8] = *(const uint4*)src;
    }
    __syncthreads();
    f32x4 ar = {0.f, 0.f, 0.f, 0.f}, ai = {0.f, 0.f, 0.f, 0.f};
    int aoB = (wo0 + arow) * 136 + kgrp;
    int boB = (wb0 + arow) * 136 + kgrp;
#pragma unroll
    for (int kg = 0; kg < 4; kg++) {
        int ao = aoB + kg * 32;
        int bo = boB + kg * 32;
        bf16x8 Wr1 = *(const bf16x8*)&POOL[0 * 4352 + ao];
        bf16x8 Wr2 = *(const bf16x8*)&POOL[1 * 4352 + ao];
        bf16x8 Wi1 = *(const bf16x8*)&POOL[2 * 4352 + ao];
        bf16x8 Wi2 = *(const bf16x8*)&POOL[3 * 4352 + ao];
        bf16x8 Xr1 = *(const bf16x8*)&POOL[4 * 4352 + bo];
        bf16x8 Xr2 = *(const bf16x8*)&POOL[5 * 4352 + bo];
        bf16x8 Xi1 = *(const bf16x8*)&POOL[6 * 4352 + bo];
        bf16x8 Xi2 = *(const bf16x8*)&POOL[7 * 4352 + bo];
        bf16x8 nWi1 = negbf(Wi1), nWi2 = negbf(Wi2);
        ar = MFMA16(Wr1, Xr1, ar); ar = MFMA16(Wr1, Xr2, ar); ar = MFMA16(Wr2, Xr1, ar);
        ar = MFMA16(nWi1, Xi1, ar); ar = MFMA16(nWi1, Xi2, ar); ar = MFMA16(nWi2, Xi1, ar);
        ai = MFMA16(Wi1, Xr1, ai); ai = MFMA16(Wi1, Xr2, ai); ai = MFMA16(Wi2, Xr1, ai);
        ai = MFMA16(Wr1, Xi1, ai); ai = MFMA16(Wr1, Xi2, ai); ai = MFMA16(Wr2, Xi1, ai);
    }
    int ob = oq * 32 + wo0 + (l >> 4) * 4;
    int bb = wb0 + (l & 15);
#pragma unroll
    for (int j = 0; j < 4; j++) {
        size_t o = ((size_t)bb * 128 + ob + j) * 128;
        y1[o + m] = f2bf_hi(ar[j]); y2[o + m] = f2bf_lo(ar[j]);
        y1[o + 64 + m] = f2bf_hi(ai[j]); y2[o + 64 + m] = f2bf_lo(ai[j]);
    }
}

// ---------------------------------------------------------------------------
// idft+conv (MFMA, depth-3): C[o][r] = [Y|CW](o,256)*[GT;ht](256,r)+bias,GELU.
// grid (8 rt, 2 ot, 32 b). T-transpose epilogue writes htc when wtr.
// ---------------------------------------------------------------------------
__global__ __launch_bounds__(256) void idft_conv_mfma(const u16* __restrict__ y1, const u16* __restrict__ y2,
        const u16* __restrict__ gt1, const u16* __restrict__ gt2,
        const u16* __restrict__ hc1, const u16* __restrict__ hc2,
        const u16* __restrict__ cw1, const u16* __restrict__ cw2,
        const float* __restrict__ conv_b,
        u16* __restrict__ hn1, u16* __restrict__ hn2,
        u16* __restrict__ htc1, u16* __restrict__ htc2, int layer, int wtr) {
    __shared__ __align__(16) u16 A1[2][2560], A2[2][2560];
    __shared__ __align__(16) u16 B1[2][2560], B2[2][2560];
    __shared__ __align__(16) u16 T1[64 * 66], T2[64 * 66];
    int rt = blockIdx.x * 64, ot = blockIdx.y * 64, b = blockIdx.z;
    int tid = threadIdx.x, wid = tid >> 6, l = tid & 63;
    int wo0 = (wid >> 1) * 32, wr0 = (wid & 1) * 32;
    int arow = (l & 15), kgrp = (l >> 4) * 8;
    int srow = (tid >> 2) & 63, sseg = tid & 3;
    int soff = srow * 40 + sseg * 8;
    const u16* ya = y1 + ((size_t)b * 128 + ot + srow) * 128 + sseg * 8;
    const u16* yb = y2 + ((size_t)b * 128 + ot + srow) * 128 + sseg * 8;
    const u16* ca = cw1 + ((size_t)layer * 128 + ot + srow) * 128 + sseg * 8;
    const u16* cb = cw2 + ((size_t)layer * 128 + ot + srow) * 128 + sseg * 8;
    const u16* ga = gt1 + (size_t)(rt + srow) * 128 + sseg * 8;
    const u16* gb = gt2 + (size_t)(rt + srow) * 128 + sseg * 8;
    const u16* ha = hc1 + ((size_t)b * 512 + rt + srow) * 128 + sseg * 8;
    const u16* hb = hc2 + ((size_t)b * 512 + rt + srow) * 128 + sseg * 8;
    f32x4 acc[2][2] = {{{0.f,0.f,0.f,0.f},{0.f,0.f,0.f,0.f}},{{0.f,0.f,0.f,0.f},{0.f,0.f,0.f,0.f}}};
    uint4 raO0, raO1, rbO0, rbO1, raE0, raE1, rbE0, rbE1;
#define IDFT_LOAD(chk, Ra0, Ra1, Rb0, Rb1)                                    \
    {   int k0_ = ((chk) & 3) * 32;                                           \
        if ((chk) < 4) {                                                      \
            Ra0 = *(const uint4*)(ya + k0_); Ra1 = *(const uint4*)(yb + k0_); \
            Rb0 = *(const uint4*)(ga + k0_); Rb1 = *(const uint4*)(gb + k0_); \
        } else {                                                              \
            Ra0 = *(const uint4*)(ca + k0_); Ra1 = *(const uint4*)(cb + k0_); \
            Rb0 = *(const uint4*)(ha + k0_); Rb1 = *(const uint4*)(hb + k0_); \
        } }
#define IDFT_STORE(BUF, Ra0, Ra1, Rb0, Rb1)                                   \
    {   *(uint4*)(A1[BUF] + soff) = Ra0; *(uint4*)(A2[BUF] + soff) = Ra1;     \
        *(uint4*)(B1[BUF] + soff) = Rb0; *(uint4*)(B2[BUF] + soff) = Rb1; }
#define IDFT_COMPUTE(BUF)                                                     \
    {   bf16x8 bfr[2][2];                                                     \
        _Pragma("unroll")                                                     \
        for (int rf = 0; rf < 2; rf++) {                                      \
            bfr[rf][0] = *(const bf16x8*)&B1[BUF][(wr0 + rf * 16 + arow) * 40 + kgrp]; \
            bfr[rf][1] = *(const bf16x8*)&B2[BUF][(wr0 + rf * 16 + arow) * 40 + kgrp]; \
        }                                                                     \
        _Pragma("unroll")                                                     \
        for (int of = 0; of < 2; of++) {                                      \
            bf16x8 a1 = *(const bf16x8*)&A1[BUF][(wo0 + of * 16 + arow) * 40 + kgrp]; \
            bf16x8 a2 = *(const bf16x8*)&A2[BUF][(wo0 + of * 16 + arow) * 40 + kgrp]; \
            _Pragma("unroll")                                                 \
            for (int rf = 0; rf < 2; rf++) {                                  \
                acc[of][rf] = MFMA16(a1, bfr[rf][0], acc[of][rf]);            \
                acc[of][rf] = MFMA16(a1, bfr[rf][1], acc[of][rf]);            \
                acc[of][rf] = MFMA16(a2, bfr[rf][0], acc[of][rf]);            \
            }                                                                 \
        } }
    IDFT_LOAD(0, raO0, raO1, rbO0, rbO1)
    IDFT_STORE(0, raO0, raO1, rbO0, rbO1)
    IDFT_LOAD(1, raO0, raO1, rbO0, rbO1)
    IDFT_LOAD(2, raE0, raE1, rbE0, rbE1)
    __syncthreads();
    for (int k = 0; k < 8; k += 2) {
        IDFT_COMPUTE(0)
        IDFT_STORE(1, raO0, raO1, rbO0, rbO1)
        if (k < 5) IDFT_LOAD(k + 3, raO0, raO1, rbO0, rbO1)
        __syncthreads();
        IDFT_COMPUTE(1)
        if (k < 6) {
            IDFT_STORE(0, raE0, raE1, rbE0, rbE1)
            if (k < 4) IDFT_LOAD(k + 4, raE0, raE1, rbE0, rbE1)
        }
        __syncthreads();
    }
#undef IDFT_LOAD
#undef IDFT_STORE
#undef IDFT_COMPUTE
#pragma unroll
    for (int of = 0; of < 2; of++) {
        int obl = wo0 + of * 16 + (l >> 4) * 4;
        int ob = ot + obl;
#pragma unroll
        for (int rf = 0; rf < 2; rf++) {
            int rloc = wr0 + rf * 16 + (l & 15);
            int r = rt + rloc;
            float v0 = gelu_exact(acc[of][rf][0] + conv_b[layer * 128 + ob + 0]);
            float v1 = gelu_exact(acc[of][rf][1] + conv_b[layer * 128 + ob + 1]);
            float v2 = gelu_exact(acc[of][rf][2] + conv_b[layer * 128 + ob + 2]);
            float v3 = gelu_exact(acc[of][rf][3] + conv_b[layer * 128 + ob + 3]);
            ushort4 hv, lv;
            hv.x = f2bf_hi(v0); hv.y = f2bf_hi(v1); hv.z = f2bf_hi(v2); hv.w = f2bf_hi(v3);
            lv.x = f2bf_lo(v0); lv.y = f2bf_lo(v1); lv.z = f2bf_lo(v2); lv.w = f2bf_lo(v3);
            size_t off = ((size_t)b * 512 + r) * 128 + ob;
            *(ushort4*)&hn1[off] = hv;
            *(ushort4*)&hn2[off] = lv;
            if (wtr) {
                T1[(obl + 0) * 66 + rloc] = hv.x; T1[(obl + 1) * 66 + rloc] = hv.y;
                T1[(obl + 2) * 66 + rloc] = hv.z; T1[(obl + 3) * 66 + rloc] = hv.w;
                T2[(obl + 0) * 66 + rloc] = lv.x; T2[(obl + 1) * 66 + rloc] = lv.y;
                T2[(obl + 2) * 66 + rloc] = lv.z; T2[(obl + 3) * 66 + rloc] = lv.w;
            }
        }
    }
    if (wtr) {
        __syncthreads();
#pragma unroll
        for (int q = 0; q < 8; q++) {
            int t = tid + q * 256;
            int o = t >> 5, ru = t & 31;
            u32 vh = *(const u32*)&T1[o * 66 + ru * 2];
            u32 vl = *(const u32*)&T2[o * 66 + ru * 2];
            size_t off = ((size_t)b * 128 + ot + o) * 512 + rt + ru * 2;
            *(u32*)&htc1[off] = vh;
            *(u32*)&htc2[off] = vl;
        }
    }
}

// ---------------------------------------------------------------------------
// head (MFMA) + fused fc0 for next step. grid 256 blocks, 4 waves x 16 rows.
// acc[16] fully static-indexed (full unrolls) -> register resident.
// ---------------------------------------------------------------------------
__global__ __launch_bounds__(256) void head_mfma(const u16* __restrict__ ht1, const u16* __restrict__ ht2,
        const u16* __restrict__ f11, const u16* __restrict__ f12,
        const float* __restrict__ fc1_b, const float* __restrict__ fc2_w,
        const float* __restrict__ fc2_b,
        const float* __restrict__ t_grid, const float* __restrict__ fc0_w,
        const float* __restrict__ fc0_b,
        float* __restrict__ seq, float* __restrict__ preds,
        u16* __restrict__ nht1, u16* __restrict__ nht2,
        u16* __restrict__ nhtc1, u16* __restrict__ nhtc2,
        int step, int do_fc0) {
    __shared__ __align__(16) u16 POOL[25600];     // 51.2 KB, aliased in epilogue
    __shared__ float fc2s[256], fc1bs[256];
    u16* HA1 = POOL;                // 256*40
    u16* HA2 = POOL + 10240;
    u16* HB1 = POOL + 20480;        // 64*40
    u16* HB2 = POOL + 23040;
    int blk = blockIdx.x;
    int b = blk >> 3, r0 = (blk & 7) * 64;
    int tid = threadIdx.x, wid = tid >> 6, l = tid & 63;
    fc2s[tid] = fc2_w[tid];
    fc1bs[tid] = fc1_b[tid];
    int arow = l & 15, kgrp = (l >> 4) * 8;
    f32x4 acc[16];
#pragma unroll
    for (int jf = 0; jf < 16; jf++) acc[jf] = (f32x4){0.f, 0.f, 0.f, 0.f};
    for (int k0 = 0; k0 < 128; k0 += 32) {
        __syncthreads();
#pragma unroll
        for (int q = 0; q < 8; q++) {
            int t = tid + q * 256;
            int pl = t >> 10, j = (t >> 2) & 255, seg = t & 3;
            const u16* src = (pl ? f12 : f11) + (size_t)j * 128 + k0 + seg * 8;
            *(uint4*)((pl ? HA2 : HA1) + j * 40 + seg * 8) = *(const uint4*)src;
        }
#pragma unroll
        for (int q = 0; q < 2; q++) {
            int t = tid + q * 256;
            int pl = t >> 8, rr = (t >> 2) & 63, seg = t & 3;
            const u16* src = (pl ? ht2 : ht1) + ((size_t)b * 512 + r0 + rr) * 128 + k0 + seg * 8;
            *(uint4*)((pl ? HB2 : HB1) + rr * 40 + seg * 8) = *(const uint4*)src;
        }
        __syncthreads();
        int bo = (wid * 16 + arow) * 40 + kgrp;
        bf16x8 b1 = *(const bf16x8*)&HB1[bo];
        bf16x8 b2 = *(const bf16x8*)&HB2[bo];
#pragma unroll
        for (int jf = 0; jf < 16; jf++) {
            int ao = (jf * 16 + arow) * 40 + kgrp;
            bf16x8 a1 = *(const bf16x8*)&HA1[ao];
            bf16x8 a2 = *(const bf16x8*)&HA2[ao];
            acc[jf] = MFMA16(a1, b1, acc[jf]);
            acc[jf] = MFMA16(a1, b2, acc[jf]);
            acc[jf] = MFMA16(a2, b1, acc[jf]);
        }
    }
    __syncthreads();   // all POOL reads done; safe to alias below
    float dx = 0.0f;
#pragma unroll
    for (int jf = 0; jf < 16; jf++) {
        int jbase = jf * 16 + (l >> 4) * 4;
#pragma unroll
        for (int jj = 0; jj < 4; jj++) {
            int j = jbase + jj;
            dx += gelu_exact(acc[jf][jj] + fc1bs[j]) * fc2s[j];
        }
    }
    dx += __shfl_xor(dx, 16);
    dx += __shfl_xor(dx, 32);
    bool zlane = ((l >> 4) == 0);
    int rml = wid * 16 + arow;
    float zn = 0.0f;
    if (zlane) {
        int r = r0 + rml;
        zn = seq[((size_t)b * SEQROWS + step + 23) * NR + r] + dx + fc2_b[0];
        seq[((size_t)b * SEQROWS + step + 24) * NR + r] = zn;
        preds[((size_t)b * NSTEPS + step) * NR + r] = zn;
    }
    if (!do_fc0) return;
    float* win = (float*)POOL;                 // [24][64]
    float* wl  = (float*)POOL + 2048;          // [28][128]
    float* bl  = (float*)POOL + 2048 + 3584;   // [128]
    for (int t = tid; t < 23 * 64; t += 256) {
        int tr = t >> 6, c = t & 63;
        win[tr * 64 + c] = seq[((size_t)b * SEQROWS + step + 1 + tr) * NR + r0 + c];
    }
    for (int t = tid; t < 28 * 128; t += 256) wl[t] = fc0_w[t];
    if (tid < 128) bl[tid] = fc0_b[tid];
    if (zlane) win[23 * 64 + rml] = zn;
    __syncthreads();
    int lane = tid & 63, wq = tid >> 6;
    int r = r0 + lane;
    float sv[24];
#pragma unroll
    for (int t = 0; t < 24; t++) sv[t] = win[t * 64 + lane];
    float tt = t_grid[b * 24 + 23] + (float)(step + 2);
    float ang24 = 6.28318530717958647692f * tt * (1.0f / 24.0f);
    float ang168 = 6.28318530717958647692f * tt * (1.0f / 168.0f);
    float s24 = sinf(ang24), c24 = cosf(ang24), s168 = sinf(ang168);
    float xc = (float)r * (1.0f / 511.0f);
    size_t rowoff = ((size_t)b * NR + r) * NW;
#pragma unroll 2
    for (int w0 = 0; w0 < 32; w0 += 2) {
        float acc2[2];
#pragma unroll
        for (int q = 0; q < 2; q++) {
            int w = wq * 32 + w0 + q;
            float a = bl[w];
#pragma unroll
            for (int t = 0; t < 24; t++) a += sv[t] * wl[t * 128 + w];
            a += s24 * wl[24 * 128 + w] + c24 * wl[25 * 128 + w]
               + s168 * wl[26 * 128 + w] + xc * wl[27 * 128 + w];
            acc2[q] = a;
        }
        u16 h0 = f2bf_hi(acc2[0]), h1 = f2bf_hi(acc2[1]);
        u16 l0 = f2bf_lo(acc2[0]), l1 = f2bf_lo(acc2[1]);
        size_t off = rowoff + wq * 32 + w0;
        *(u32*)&nht1[off] = (u32)h0 | ((u32)h1 << 16);
        *(u32*)&nht2[off] = (u32)l0 | ((u32)l1 << 16);
        int w = wq * 32 + w0;
        size_t coff = ((size_t)b * 128 + w) * 512 + r;
        nhtc1[coff] = h0; nhtc1[coff + 512] = h1;
        nhtc2[coff] = l0; nhtc2[coff + 512] = l1;
    }
}

// ---------------------------------------------------------------------------
extern "C" void kernel_launch(void* const* d_in, const int* in_sizes, int n_in,
                              void* d_out, int out_size, void* d_ws, size_t ws_size,
                              hipStream_t stream) {
    (void)in_sizes; (void)n_in; (void)out_size; (void)ws_size;
    const float* z       = (const float*)d_in[0];
    const float* t_grid  = (const float*)d_in[1];
    const float* fc0_w   = (const float*)d_in[2];
    const float* fc0_b   = (const float*)d_in[3];
    const float* spec_wr = (const float*)d_in[4];
    const float* spec_wi = (const float*)d_in[5];
    const float* conv_w  = (const float*)d_in[6];
    const float* conv_b  = (const float*)d_in[7];
    const float* fc1_w   = (const float*)d_in[8];
    const float* fc1_b   = (const float*)d_in[9];
    const float* fc2_w   = (const float*)d_in[10];
    const float* fc2_b   = (const float*)d_in[11];
    float* preds = (float*)d_out;

    char* p = (char*)d_ws;
    float* seq = (float*)p;  p += (size_t)NB * SEQROWS * NR * 4;
    u16* ht1 = (u16*)p;  p += (size_t)2 * NB * NR * NW * 2;   // [2 buf][b][r][c] hi
    u16* ht2 = (u16*)p;  p += (size_t)2 * NB * NR * NW * 2;   // lo
    u16* htc1 = (u16*)p; p += (size_t)NB * NW * NR * 2;       // [b][c][r] hi
    u16* htc2 = (u16*)p; p += (size_t)NB * NW * NR * 2;       // lo
    u16* x1  = (u16*)p;  p += (size_t)128 * 4096 * 2;
    u16* x2  = (u16*)p;  p += (size_t)128 * 4096 * 2;
    u16* y1  = (u16*)p;  p += (size_t)NB * NW * 128 * 2;
    u16* y2  = (u16*)p;  p += (size_t)NB * NW * 128 * 2;
    u16* f1  = (u16*)p;  p += (size_t)128 * 512 * 2;
    u16* f2  = (u16*)p;  p += (size_t)128 * 512 * 2;
    u16* gt1 = (u16*)p;  p += (size_t)512 * 128 * 2;
    u16* gt2 = (u16*)p;  p += (size_t)512 * 128 * 2;
    u16* wr1 = (u16*)p;  p += (size_t)NLAY * NM * NW * NW * 2;
    u16* wr2 = (u16*)p;  p += (size_t)NLAY * NM * NW * NW * 2;
    u16* wi1 = (u16*)p;  p += (size_t)NLAY * NM * NW * NW * 2;
    u16* wi2 = (u16*)p;  p += (size_t)NLAY * NM * NW * NW * 2;
    u16* cw1 = (u16*)p;  p += (size_t)NLAY * NW * NW * 2;
    u16* cw2 = (u16*)p;  p += (size_t)NLAY * NW * NW * 2;
    u16* f11 = (u16*)p;  p += (size_t)256 * 128 * 2;
    u16* f12 = (u16*)p;  p += (size_t)256 * 128 * 2;

    const size_t htplane = (size_t)NB * NR * NW;

    build_tables_planes<<<256, 256, 0, stream>>>(f1, f2, gt1, gt2);
    prep_specw<<<512, 256, 0, stream>>>(spec_wr, spec_wi, wr1, wr2, wi1, wi2);
    prep_cw<<<256, 256, 0, stream>>>(conv_w, cw1, cw2);
    prep_fc1t<<<128, 256, 0, stream>>>(fc1_w, f11, f12);
    init_seq_kernel<<<(NB * NTH * NR) / 256, 256, 0, stream>>>(z, seq);

    for (int step = 0; step < NSTEPS; step++) {
        if (step == 0) {
            fc0_kernel<<<dim3(8, 32), 256, 0, stream>>>(seq, t_grid, fc0_w, fc0_b,
                                                        ht1, ht2, htc1, htc2, step);
        }
        int cur = 0;
        for (int l = 0; l < NLAY; l++) {
            const u16* hc1 = ht1 + (size_t)cur * htplane;
            const u16* hc2 = ht2 + (size_t)cur * htplane;
            u16* hn1 = ht1 + (size_t)(cur ^ 1) * htplane;
            u16* hn2 = ht2 + (size_t)(cur ^ 1) * htplane;
            dft_mfma<<<dim3(128, 4), 256, 0, stream>>>(f1, f2, htc1, htc2, x1, x2);
            modemix_mfma<<<dim3(64, 4), 256, 0, stream>>>(x1, x2, wr1, wr2, wi1, wi2,
                                                          y1, y2, l);
            idft_conv_mfma<<<dim3(8, 2, 32), 256, 0, stream>>>(y1, y2, gt1, gt2,
                                                               hc1, hc2, cw1, cw2,
                                                               conv_b, hn1, hn2,
                                                               htc1, htc2, l, (l < 3) ? 1 : 0);
            cur ^= 1;
        }
        head_mfma<<<256, 256, 0, stream>>>(ht1, ht2, f11, f12, fc1_b, fc2_w, fc2_b,
                                           t_grid, fc0_w, fc0_b, seq, preds,
                                           ht1, ht2, htc1, htc2,
                                           step, (step < NSTEPS - 1) ? 1 : 0);
    }
}